// Round 15
// baseline (173.138 us; speedup 1.0000x reference)
//
#include <hip/hip_runtime.h>
#include <hip/hip_bf16.h>
#include <hip/hip_fp16.h>

// Problem: B=N=1024, in_f=1024, OUT_F=32, KD=8
// R14: MEASUREMENT ROUND (R13 pipeline verbatim):
//   gemm_mfma core repeated x16 (accs chained, store acc/16 once)
//   pairwise12 loop repeated x8 (idempotent re-store)
// Solve: total = 40.2 + 7*loop12 + 15*gcore; both surface in rocprof top-5.

#define N_ROWS 1024
#define IN_F   1024
#define OUT_C  1056
#define OK     256   // OUT_F*KD
#define KS     8     // K-split factor
#define KC     128   // K-chunk = IN_F/KS
#define LOG2E  1.44269504f

typedef __attribute__((ext_vector_type(8))) short bf16x8;
typedef __attribute__((ext_vector_type(4))) float f32x4;

__device__ __forceinline__ unsigned short f2bf(float f) {
  unsigned u = __float_as_uint(f);
  u = (u + 0x7FFFu + ((u >> 16) & 1u)) >> 16;   // RNE
  return (unsigned short)u;
}

__device__ __forceinline__ float fast_exp2(float x) {
#if __has_builtin(__builtin_amdgcn_exp2f)
  return __builtin_amdgcn_exp2f(x);   // v_exp_f32 = 2^x
#else
  return __expf(x * 0.6931472f);
#endif
}

union HQ { uint4 q; __half2 h[4]; };

// ---------------- kernel 1: prep (R13 verbatim) ------------------------------
__global__ __launch_bounds__(256) void prep_kernel(
    const float* __restrict__ x, const float* __restrict__ T,
    float* __restrict__ out, unsigned short* __restrict__ xb,
    unsigned short* __restrict__ Tt) {
  const int b = blockIdx.x, t = threadIdx.x;
  if (b < 512) {
#pragma unroll
    for (int u = 0; u < 2; ++u) {
      int idx = b * 512 + u * 256 + t;          // 262144 float4 groups
      int row = idx >> 8, col4 = idx & 255;     // rows 2b, 2b+1
      float4 v = *reinterpret_cast<const float4*>(x + (size_t)row * IN_F + col4 * 4);
      *reinterpret_cast<float4*>(out + (size_t)row * OUT_C + col4 * 4) = v;
      ushort4 h = make_ushort4(f2bf(v.x), f2bf(v.y), f2bf(v.z), f2bf(v.w));
      *reinterpret_cast<ushort4*>(xb + (size_t)row * IN_F + col4 * 4) = h;
    }
  } else {
    int c = (b - 512) * 4 + (t >> 6);   // 0..255
    int g = t & 63;
#pragma unroll
    for (int u = 0; u < 2; ++u) {
      int k0 = g * 16 + u * 8;
      unsigned short h[8];
#pragma unroll
      for (int j = 0; j < 8; ++j)
        h[j] = f2bf(T[(size_t)(k0 + j) * OK + c]);
      *reinterpret_cast<uint4*>(Tt + (size_t)c * IN_F + k0) =
          *reinterpret_cast<const uint4*>(h);
    }
  }
}

// ---------------- kernel 2: bf16 MFMA GEMM, core x16 (measurement) -----------
__global__ __launch_bounds__(256) void gemm_mfma_kernel(
    const unsigned short* __restrict__ xb,  // [1024][1024] bf16
    const unsigned short* __restrict__ Tt,  // [256][1024] bf16 (T transposed)
    float* __restrict__ part) {             // [KS][1024][256]
  __shared__ unsigned short asw[64 * 128];
  __shared__ unsigned short bsw[64 * 128];
  const int m0 = blockIdx.x * 64;
  const int n0 = blockIdx.y * 64;
  const int ks = blockIdx.z;
  const int t  = threadIdx.x;

  const int l  = t & 63, w = t >> 6;
  const int lr = l & 15, lg = l >> 4;
  f32x4 acc0 = {0.f, 0.f, 0.f, 0.f};
  f32x4 acc1 = {0.f, 0.f, 0.f, 0.f};
  f32x4 acc2 = {0.f, 0.f, 0.f, 0.f};
  f32x4 acc3 = {0.f, 0.f, 0.f, 0.f};
  const int arow = w * 16 + lr;
  const int aswz = arow & 15;

  for (int rep = 0; rep < 16; ++rep) {
    asm volatile("" ::: "memory");   // force re-stage + re-read each rep
#pragma unroll
    for (int u = 0; u < 4; ++u) {
      int idx = t + 256 * u;
      int row = idx >> 4, slot = idx & 15;
      uint4 va = *reinterpret_cast<const uint4*>(
          xb + (size_t)(m0 + row) * IN_F + ks * KC + slot * 8);
      *reinterpret_cast<uint4*>(asw + row * 128 + ((slot ^ (row & 15)) * 8)) = va;
      uint4 vb = *reinterpret_cast<const uint4*>(
          Tt + (size_t)(n0 + row) * IN_F + ks * KC + slot * 8);
      *reinterpret_cast<uint4*>(bsw + row * 128 + ((slot ^ (row & 15)) * 8)) = vb;
    }
    __syncthreads();

#pragma unroll
    for (int kk = 0; kk < 4; ++kk) {
      int slotA = kk * 4 + lg;
      bf16x8 a = *reinterpret_cast<const bf16x8*>(
          asw + arow * 128 + ((slotA ^ aswz) * 8));
      int sb = (slotA ^ lr) * 8;
      bf16x8 b0 = *reinterpret_cast<const bf16x8*>(bsw + (lr)      * 128 + sb);
      bf16x8 b1 = *reinterpret_cast<const bf16x8*>(bsw + (16 + lr) * 128 + sb);
      bf16x8 b2 = *reinterpret_cast<const bf16x8*>(bsw + (32 + lr) * 128 + sb);
      bf16x8 b3 = *reinterpret_cast<const bf16x8*>(bsw + (48 + lr) * 128 + sb);
      acc0 = __builtin_amdgcn_mfma_f32_16x16x32_bf16(a, b0, acc0, 0, 0, 0);
      acc1 = __builtin_amdgcn_mfma_f32_16x16x32_bf16(a, b1, acc1, 0, 0, 0);
      acc2 = __builtin_amdgcn_mfma_f32_16x16x32_bf16(a, b2, acc2, 0, 0, 0);
      acc3 = __builtin_amdgcn_mfma_f32_16x16x32_bf16(a, b3, acc3, 0, 0, 0);
    }
    __syncthreads();
  }

  // accs hold 16x the tile sum (tiny fp re-association error, ~1e-5 abs in M)
  float* dst = part + (size_t)ks * (N_ROWS * OK)
             + (size_t)(m0 + w * 16 + lg * 4) * OK + n0 + lr;
#pragma unroll
  for (int r = 0; r < 4; ++r) {
    dst[(size_t)r * OK]      = acc0[r] * 0.0625f;
    dst[(size_t)r * OK + 16] = acc1[r] * 0.0625f;
    dst[(size_t)r * OK + 32] = acc2[r] * 0.0625f;
    dst[(size_t)r * OK + 48] = acc3[r] * 0.0625f;
  }
}

// ---------------- kernel 3: reduce -> transposed f16 Mt (R13 verbatim) -------
__global__ __launch_bounds__(256) void reduce_kernel(
    const float* __restrict__ part, __half* __restrict__ Mt) {
  int g = blockIdx.x * 256 + threadIdx.x;    // 65536 float4 groups
  const float4* p = reinterpret_cast<const float4*>(part);
  float4 s = p[g];
#pragma unroll
  for (int sl = 1; sl < KS; ++sl) {
    float4 v = p[g + (size_t)sl * (N_ROWS * OK / 4)];
    s.x += v.x; s.y += v.y; s.z += v.z; s.w += v.w;
  }
  int n = g >> 6, c = (g & 63) * 4;
  int o = c >> 3, k = c & 7;
  __half2 h01 = __floats2half2_rn(s.x * LOG2E, s.y * LOG2E);
  __half2 h23 = __floats2half2_rn(s.z * LOG2E, s.w * LOG2E);
  uint2 wv = make_uint2(*reinterpret_cast<unsigned*>(&h01),
                        *reinterpret_cast<unsigned*>(&h23));
  *reinterpret_cast<uint2*>(Mt + (size_t)o * (N_ROWS * 8) + n * 8 + k) = wv;
}

// ---------------- fallback GEMM (small ws) -----------------------------------
#define BK 16
__global__ __launch_bounds__(256) void gemm32_kernel(
    const float* __restrict__ A, const float* __restrict__ Bm, float* __restrict__ M) {
  __shared__ float as2[BK][32];
  __shared__ float bs2[BK][32];
  int m0 = blockIdx.x * 32;
  int n0 = blockIdx.y * 32;
  int t  = threadIdx.x;
  int ty = t >> 4, tx = t & 15;
  float c00 = 0.f, c01 = 0.f, c10 = 0.f, c11 = 0.f;
  for (int k0 = 0; k0 < IN_F; k0 += BK) {
    if (t < 128) {
      int row = t >> 2, q = t & 3;
      float4 v = *reinterpret_cast<const float4*>(A + (size_t)(m0 + row) * IN_F + k0 + q * 4);
      as2[q * 4 + 0][row] = v.x; as2[q * 4 + 1][row] = v.y;
      as2[q * 4 + 2][row] = v.z; as2[q * 4 + 3][row] = v.w;
    } else {
      int tt = t - 128;
      int row = tt >> 3, q = tt & 7;
      float4 v = *reinterpret_cast<const float4*>(Bm + (size_t)(k0 + row) * OK + n0 + q * 4);
      *reinterpret_cast<float4*>(&bs2[row][q * 4]) = v;
    }
    __syncthreads();
#pragma unroll
    for (int kk = 0; kk < BK; ++kk) {
      float2 a = *reinterpret_cast<const float2*>(&as2[kk][ty * 2]);
      float2 b = *reinterpret_cast<const float2*>(&bs2[kk][tx * 2]);
      c00 += a.x * b.x; c01 += a.x * b.y;
      c10 += a.y * b.x; c11 += a.y * b.y;
    }
    __syncthreads();
  }
  int r = m0 + ty * 2, c = n0 + tx * 2;
  M[(size_t)r * OK + c]           = c00 * LOG2E;
  M[(size_t)r * OK + c + 1]       = c01 * LOG2E;
  M[(size_t)(r + 1) * OK + c]     = c10 * LOG2E;
  M[(size_t)(r + 1) * OK + c + 1] = c11 * LOG2E;
}

// ---------------- kernel 4: pairwise v12, loop x8 (measurement) --------------
__global__ __launch_bounds__(256) void pairwise12_kernel(
    const __half* __restrict__ Mt, float* __restrict__ out) {
  __shared__ uint4 sm[N_ROWS];      // 16 KB
  __shared__ float red[4][64];

  int o  = blockIdx.x;
  int jt = blockIdx.y;
  int t  = threadIdx.x;

  const uint4* src = reinterpret_cast<const uint4*>(Mt + (size_t)o * (N_ROWS * 8));
#pragma unroll
  for (int u = 0; u < 4; ++u)
    sm[t + 256 * u] = src[t + 256 * u];
  __syncthreads();

  int jl = t & 63, s = t >> 6;
  int j  = jt * 64 + jl;

  HQ ju; ju.q = sm[j];
  __half2 r0 = ju.h[0], r1 = ju.h[1], r2 = ju.h[2], r3 = ju.h[3];
  const uint4* base = &sm[s * 256];

  for (int rep = 0; rep < 8; ++rep) {
    float acc = 0.f;
    asm volatile("" : "+v"(acc));   // opaque: loop re-executes each rep
#pragma unroll 4
    for (int i = 0; i < 256; ++i) {
      HQ u_; u_.q = base[i];
      __half2 d2 = __hadd2(
          __hadd2(__habs2(__hsub2(u_.h[0], r0)), __habs2(__hsub2(u_.h[1], r1))),
          __hadd2(__habs2(__hsub2(u_.h[2], r2)), __habs2(__hsub2(u_.h[3], r3))));
      float d = __low2float(d2) + __high2float(d2);
      acc += fast_exp2(-d);
    }
    if ((j >> 8) == s) acc -= 1.0f;

    red[s][jl] = acc;
    __syncthreads();
    if (t < 64) {
      float v = red[0][t] + red[1][t] + red[2][t] + red[3][t];
      int jj = jt * 64 + t;
      out[(size_t)jj * OUT_C + 1024 + o] = v;   // same value every rep
    }
    __syncthreads();
  }
}

// ---------------- fallback pairwise + copy -----------------------------------
__global__ __launch_bounds__(256) void pairwise_kernel(
    const float* __restrict__ M, float* __restrict__ out) {
  __shared__ float sm[N_ROWS][8];
  __shared__ float red[4][64];
  int o  = blockIdx.x;
  int jt = blockIdx.y;
  int t  = threadIdx.x;
#pragma unroll
  for (int idx = t; idx < 2048; idx += 256) {
    int row = idx >> 1, half = idx & 1;
    *reinterpret_cast<float4*>(&sm[row][half * 4]) =
        *reinterpret_cast<const float4*>(M + (size_t)row * OK + o * 8 + half * 4);
  }
  __syncthreads();
  int jl = t & 63, s = t >> 6;
  int j  = jt * 64 + jl;
  float4 ra = *reinterpret_cast<const float4*>(&sm[j][0]);
  float4 rb = *reinterpret_cast<const float4*>(&sm[j][4]);
  float acc = 0.f;
  const float* base = &sm[s * 256][0];
#pragma unroll 4
  for (int i = 0; i < 256; ++i) {
    float4 va = *reinterpret_cast<const float4*>(base + i * 8);
    float4 vb = *reinterpret_cast<const float4*>(base + i * 8 + 4);
    float d = fabsf(va.x - ra.x) + fabsf(va.y - ra.y) +
              fabsf(va.z - ra.z) + fabsf(va.w - ra.w) +
              fabsf(vb.x - rb.x) + fabsf(vb.y - rb.y) +
              fabsf(vb.z - rb.z) + fabsf(vb.w - rb.w);
    acc += fast_exp2(-d);
  }
  if ((j >> 8) == s) acc -= 1.0f;
  red[s][jl] = acc;
  __syncthreads();
  if (t < 64) {
    float v = red[0][t] + red[1][t] + red[2][t] + red[3][t];
    int jj = jt * 64 + t;
    out[(size_t)jj * OUT_C + 1024 + o] = v;
  }
}

__global__ __launch_bounds__(256) void copy_x_kernel(
    const float* __restrict__ x, float* __restrict__ out) {
  int n = blockIdx.x;
  int c = threadIdx.x * 4;
  float4 v = *reinterpret_cast<const float4*>(x + (size_t)n * IN_F + c);
  *reinterpret_cast<float4*>(out + (size_t)n * OUT_C + c) = v;
}

extern "C" void kernel_launch(void* const* d_in, const int* in_sizes, int n_in,
                              void* d_out, int out_size, void* d_ws, size_t ws_size,
                              hipStream_t stream) {
  const float* x = (const float*)d_in[0];   // [1024][1024]
  const float* T = (const float*)d_in[1];   // [1024][256]
  float* out = (float*)d_out;               // [1024][1056]

  const size_t mElems = (size_t)N_ROWS * OK;           // 262144
  const size_t needed = KS * mElems * 4                // part  8 MB
                      + mElems * 2                     // Mt  0.5 MB
                      + (size_t)N_ROWS * IN_F * 2      // xb    2 MB
                      + (size_t)OK * IN_F * 2;         // Tt  0.5 MB

  if (ws_size >= needed) {
    float* part = (float*)d_ws;
    __half* Mt  = (__half*)(part + KS * mElems);
    unsigned short* xb = (unsigned short*)(Mt + mElems);
    unsigned short* Tt = xb + (size_t)N_ROWS * IN_F;

    prep_kernel<<<dim3(576), dim3(256), 0, stream>>>(x, T, out, xb, Tt);
    gemm_mfma_kernel<<<dim3(16, 4, KS), dim3(256), 0, stream>>>(xb, Tt, part);
    reduce_kernel<<<dim3(256), dim3(256), 0, stream>>>(part, Mt);
    pairwise12_kernel<<<dim3(32, 16), dim3(256), 0, stream>>>(Mt, out);
  } else {
    float* M = (float*)d_ws;
    copy_x_kernel<<<dim3(N_ROWS), dim3(256), 0, stream>>>(x, out);
    gemm32_kernel<<<dim3(32, 8), dim3(256), 0, stream>>>(x, T, M);
    pairwise_kernel<<<dim3(32, 16), dim3(256), 0, stream>>>(M, out);
  }
}

// Round 16
// 38.396 us; speedup vs baseline: 4.5093x; 4.5093x over previous
//
#include <hip/hip_runtime.h>
#include <hip/hip_bf16.h>
#include <hip/hip_fp16.h>

// Problem: B=N=1024, in_f=1024, OUT_F=32, KD=8
// out[n][0:1024]   = x[n][:]
// M[n][o*8+k]      = sum_f x[n][f] * T[f][o*8+k]        (T flat [1024][256])
// out[n][1024+o]   = sum_{i != n} exp(-sum_k |M[i][o*8+k] - M[n][o*8+k]|)
//
// R15: pairwise v13 = v12 with NATIVE packed f16 vectors (_Float16 ext_vector,
// v_pk_add_f16 + v_and abs) replacing scalarized __half2 intrinsics.
// R14 measured: loop was ~35 VALU/iter (scalarized); packed target ~15.

#define N_ROWS 1024
#define IN_F   1024
#define OUT_C  1056
#define OK     256   // OUT_F*KD
#define KS     8     // K-split factor
#define KC     128   // K-chunk = IN_F/KS
#define LOG2E  1.44269504f

typedef __attribute__((ext_vector_type(8))) short bf16x8;
typedef __attribute__((ext_vector_type(4))) float f32x4;
typedef _Float16 hv2 __attribute__((ext_vector_type(2)));

__device__ __forceinline__ unsigned short f2bf(float f) {
  unsigned u = __float_as_uint(f);
  u = (u + 0x7FFFu + ((u >> 16) & 1u)) >> 16;   // RNE
  return (unsigned short)u;
}

__device__ __forceinline__ float fast_exp2(float x) {
#if __has_builtin(__builtin_amdgcn_exp2f)
  return __builtin_amdgcn_exp2f(x);   // v_exp_f32 = 2^x
#else
  return __expf(x * 0.6931472f);
#endif
}

// packed |.| : single v_and_b32 on the pair
__device__ __forceinline__ hv2 habs2v(hv2 v) {
  unsigned u = __builtin_bit_cast(unsigned, v) & 0x7fff7fffu;
  return __builtin_bit_cast(hv2, u);
}

union HQ { uint4 q; hv2 h[4]; };

// ---------------- kernel 1: prep (R13 verbatim) ------------------------------
__global__ __launch_bounds__(256) void prep_kernel(
    const float* __restrict__ x, const float* __restrict__ T,
    float* __restrict__ out, unsigned short* __restrict__ xb,
    unsigned short* __restrict__ Tt) {
  const int b = blockIdx.x, t = threadIdx.x;
  if (b < 512) {
#pragma unroll
    for (int u = 0; u < 2; ++u) {
      int idx = b * 512 + u * 256 + t;          // 262144 float4 groups
      int row = idx >> 8, col4 = idx & 255;     // rows 2b, 2b+1
      float4 v = *reinterpret_cast<const float4*>(x + (size_t)row * IN_F + col4 * 4);
      *reinterpret_cast<float4*>(out + (size_t)row * OUT_C + col4 * 4) = v;
      ushort4 h = make_ushort4(f2bf(v.x), f2bf(v.y), f2bf(v.z), f2bf(v.w));
      *reinterpret_cast<ushort4*>(xb + (size_t)row * IN_F + col4 * 4) = h;
    }
  } else {
    int c = (b - 512) * 4 + (t >> 6);   // 0..255
    int g = t & 63;
#pragma unroll
    for (int u = 0; u < 2; ++u) {
      int k0 = g * 16 + u * 8;
      unsigned short h[8];
#pragma unroll
      for (int j = 0; j < 8; ++j)
        h[j] = f2bf(T[(size_t)(k0 + j) * OK + c]);
      *reinterpret_cast<uint4*>(Tt + (size_t)c * IN_F + k0) =
          *reinterpret_cast<const uint4*>(h);
    }
  }
}

// ---------------- kernel 2: bf16 MFMA GEMM (R13 verbatim, single-pass) -------
__global__ __launch_bounds__(256) void gemm_mfma_kernel(
    const unsigned short* __restrict__ xb,  // [1024][1024] bf16
    const unsigned short* __restrict__ Tt,  // [256][1024] bf16 (T transposed)
    float* __restrict__ part) {             // [KS][1024][256]
  __shared__ unsigned short asw[64 * 128];
  __shared__ unsigned short bsw[64 * 128];
  const int m0 = blockIdx.x * 64;
  const int n0 = blockIdx.y * 64;
  const int ks = blockIdx.z;
  const int t  = threadIdx.x;

#pragma unroll
  for (int u = 0; u < 4; ++u) {
    int idx = t + 256 * u;
    int row = idx >> 4, slot = idx & 15;
    uint4 va = *reinterpret_cast<const uint4*>(
        xb + (size_t)(m0 + row) * IN_F + ks * KC + slot * 8);
    *reinterpret_cast<uint4*>(asw + row * 128 + ((slot ^ (row & 15)) * 8)) = va;
    uint4 vb = *reinterpret_cast<const uint4*>(
        Tt + (size_t)(n0 + row) * IN_F + ks * KC + slot * 8);
    *reinterpret_cast<uint4*>(bsw + row * 128 + ((slot ^ (row & 15)) * 8)) = vb;
  }
  __syncthreads();

  const int l  = t & 63, w = t >> 6;
  const int lr = l & 15, lg = l >> 4;
  f32x4 acc0 = {0.f, 0.f, 0.f, 0.f};
  f32x4 acc1 = {0.f, 0.f, 0.f, 0.f};
  f32x4 acc2 = {0.f, 0.f, 0.f, 0.f};
  f32x4 acc3 = {0.f, 0.f, 0.f, 0.f};

  const int arow = w * 16 + lr;
  const int aswz = arow & 15;
#pragma unroll
  for (int kk = 0; kk < 4; ++kk) {
    int slotA = kk * 4 + lg;
    bf16x8 a = *reinterpret_cast<const bf16x8*>(
        asw + arow * 128 + ((slotA ^ aswz) * 8));
    int sb = (slotA ^ lr) * 8;
    bf16x8 b0 = *reinterpret_cast<const bf16x8*>(bsw + (lr)      * 128 + sb);
    bf16x8 b1 = *reinterpret_cast<const bf16x8*>(bsw + (16 + lr) * 128 + sb);
    bf16x8 b2 = *reinterpret_cast<const bf16x8*>(bsw + (32 + lr) * 128 + sb);
    bf16x8 b3 = *reinterpret_cast<const bf16x8*>(bsw + (48 + lr) * 128 + sb);
    acc0 = __builtin_amdgcn_mfma_f32_16x16x32_bf16(a, b0, acc0, 0, 0, 0);
    acc1 = __builtin_amdgcn_mfma_f32_16x16x32_bf16(a, b1, acc1, 0, 0, 0);
    acc2 = __builtin_amdgcn_mfma_f32_16x16x32_bf16(a, b2, acc2, 0, 0, 0);
    acc3 = __builtin_amdgcn_mfma_f32_16x16x32_bf16(a, b3, acc3, 0, 0, 0);
  }

  float* dst = part + (size_t)ks * (N_ROWS * OK)
             + (size_t)(m0 + w * 16 + lg * 4) * OK + n0 + lr;
#pragma unroll
  for (int r = 0; r < 4; ++r) {
    dst[(size_t)r * OK]      = acc0[r];
    dst[(size_t)r * OK + 16] = acc1[r];
    dst[(size_t)r * OK + 32] = acc2[r];
    dst[(size_t)r * OK + 48] = acc3[r];
  }
}

// ---------------- kernel 3: reduce -> transposed f16 Mt (R13 verbatim) -------
__global__ __launch_bounds__(256) void reduce_kernel(
    const float* __restrict__ part, __half* __restrict__ Mt) {
  int g = blockIdx.x * 256 + threadIdx.x;    // 65536 float4 groups
  const float4* p = reinterpret_cast<const float4*>(part);
  float4 s = p[g];
#pragma unroll
  for (int sl = 1; sl < KS; ++sl) {
    float4 v = p[g + (size_t)sl * (N_ROWS * OK / 4)];
    s.x += v.x; s.y += v.y; s.z += v.z; s.w += v.w;
  }
  int n = g >> 6, c = (g & 63) * 4;
  int o = c >> 3, k = c & 7;
  __half2 h01 = __floats2half2_rn(s.x * LOG2E, s.y * LOG2E);
  __half2 h23 = __floats2half2_rn(s.z * LOG2E, s.w * LOG2E);
  uint2 wv = make_uint2(*reinterpret_cast<unsigned*>(&h01),
                        *reinterpret_cast<unsigned*>(&h23));
  *reinterpret_cast<uint2*>(Mt + (size_t)o * (N_ROWS * 8) + n * 8 + k) = wv;
}

// ---------------- fallback GEMM (small ws) -----------------------------------
#define BK 16
__global__ __launch_bounds__(256) void gemm32_kernel(
    const float* __restrict__ A, const float* __restrict__ Bm, float* __restrict__ M) {
  __shared__ float as2[BK][32];
  __shared__ float bs2[BK][32];
  int m0 = blockIdx.x * 32;
  int n0 = blockIdx.y * 32;
  int t  = threadIdx.x;
  int ty = t >> 4, tx = t & 15;
  float c00 = 0.f, c01 = 0.f, c10 = 0.f, c11 = 0.f;
  for (int k0 = 0; k0 < IN_F; k0 += BK) {
    if (t < 128) {
      int row = t >> 2, q = t & 3;
      float4 v = *reinterpret_cast<const float4*>(A + (size_t)(m0 + row) * IN_F + k0 + q * 4);
      as2[q * 4 + 0][row] = v.x; as2[q * 4 + 1][row] = v.y;
      as2[q * 4 + 2][row] = v.z; as2[q * 4 + 3][row] = v.w;
    } else {
      int tt = t - 128;
      int row = tt >> 3, q = tt & 7;
      float4 v = *reinterpret_cast<const float4*>(Bm + (size_t)(k0 + row) * OK + n0 + q * 4);
      *reinterpret_cast<float4*>(&bs2[row][q * 4]) = v;
    }
    __syncthreads();
#pragma unroll
    for (int kk = 0; kk < BK; ++kk) {
      float2 a = *reinterpret_cast<const float2*>(&as2[kk][ty * 2]);
      float2 b = *reinterpret_cast<const float2*>(&bs2[kk][tx * 2]);
      c00 += a.x * b.x; c01 += a.x * b.y;
      c10 += a.y * b.x; c11 += a.y * b.y;
    }
    __syncthreads();
  }
  int r = m0 + ty * 2, c = n0 + tx * 2;
  M[(size_t)r * OK + c]           = c00 * LOG2E;
  M[(size_t)r * OK + c + 1]       = c01 * LOG2E;
  M[(size_t)(r + 1) * OK + c]     = c10 * LOG2E;
  M[(size_t)(r + 1) * OK + c + 1] = c11 * LOG2E;
}

// ---------------- kernel 4: pairwise exp2(-L1) v13, native packed f16 --------
// v12 shape verbatim: grid (o:32, jt:16) = 512 blocks x 256 thr, contiguous
// 16 KB stage, 1 ds_read_b128/i. Datapath: native _Float16x2 (+,-) ->
// v_pk_add_f16; abs -> v_and_b32. Target ~15 VALU/iter (was ~35 scalarized).
__global__ __launch_bounds__(256) void pairwise13_kernel(
    const __half* __restrict__ Mt, float* __restrict__ out) {
  __shared__ uint4 sm[N_ROWS];      // 16 KB: row n = 8 halves of Mt[o][n][:]
  __shared__ float red[4][64];

  int o  = blockIdx.x;
  int jt = blockIdx.y;
  int t  = threadIdx.x;

  const uint4* src = reinterpret_cast<const uint4*>(Mt + (size_t)o * (N_ROWS * 8));
#pragma unroll
  for (int u = 0; u < 4; ++u)
    sm[t + 256 * u] = src[t + 256 * u];   // fully coalesced, b128 both sides
  __syncthreads();

  int jl = t & 63, s = t >> 6;
  int j  = jt * 64 + jl;

  HQ ju; ju.q = sm[j];
  hv2 r0 = ju.h[0], r1 = ju.h[1], r2 = ju.h[2], r3 = ju.h[3];

  float acc = 0.f;
  const uint4* base = &sm[s * 256];
#pragma unroll 8
  for (int i = 0; i < 256; ++i) {
    HQ u_; u_.q = base[i];              // one ds_read_b128
    hv2 d2 = (habs2v(u_.h[0] - r0) + habs2v(u_.h[1] - r1)) +
             (habs2v(u_.h[2] - r2) + habs2v(u_.h[3] - r3));
    float d = (float)(d2.x + d2.y);     // 1 f16 add + 1 cvt (d <= ~440, ok)
    acc += fast_exp2(-d);               // large d underflows to 0
  }
  if ((j >> 8) == s) acc -= 1.0f;       // exact self term exp2(0)=1

  red[s][jl] = acc;
  __syncthreads();

  if (t < 64) {
    float v = red[0][t] + red[1][t] + red[2][t] + red[3][t];
    int jj = jt * 64 + t;
    out[(size_t)jj * OUT_C + 1024 + o] = v;
  }
}

// ---------------- fallback pairwise (f32 M, exp2) + copy ---------------------
__global__ __launch_bounds__(256) void pairwise_kernel(
    const float* __restrict__ M, float* __restrict__ out) {
  __shared__ float sm[N_ROWS][8];
  __shared__ float red[4][64];
  int o  = blockIdx.x;
  int jt = blockIdx.y;
  int t  = threadIdx.x;
#pragma unroll
  for (int idx = t; idx < 2048; idx += 256) {
    int row = idx >> 1, half = idx & 1;
    *reinterpret_cast<float4*>(&sm[row][half * 4]) =
        *reinterpret_cast<const float4*>(M + (size_t)row * OK + o * 8 + half * 4);
  }
  __syncthreads();
  int jl = t & 63, s = t >> 6;
  int j  = jt * 64 + jl;
  float4 ra = *reinterpret_cast<const float4*>(&sm[j][0]);
  float4 rb = *reinterpret_cast<const float4*>(&sm[j][4]);
  float acc = 0.f;
  const float* base = &sm[s * 256][0];
#pragma unroll 4
  for (int i = 0; i < 256; ++i) {
    float4 va = *reinterpret_cast<const float4*>(base + i * 8);
    float4 vb = *reinterpret_cast<const float4*>(base + i * 8 + 4);
    float d = fabsf(va.x - ra.x) + fabsf(va.y - ra.y) +
              fabsf(va.z - ra.z) + fabsf(va.w - ra.w) +
              fabsf(vb.x - rb.x) + fabsf(vb.y - rb.y) +
              fabsf(vb.z - rb.z) + fabsf(vb.w - rb.w);
    acc += fast_exp2(-d);
  }
  if ((j >> 8) == s) acc -= 1.0f;
  red[s][jl] = acc;
  __syncthreads();
  if (t < 64) {
    float v = red[0][t] + red[1][t] + red[2][t] + red[3][t];
    int jj = jt * 64 + t;
    out[(size_t)jj * OUT_C + 1024 + o] = v;
  }
}

__global__ __launch_bounds__(256) void copy_x_kernel(
    const float* __restrict__ x, float* __restrict__ out) {
  int n = blockIdx.x;
  int c = threadIdx.x * 4;
  float4 v = *reinterpret_cast<const float4*>(x + (size_t)n * IN_F + c);
  *reinterpret_cast<float4*>(out + (size_t)n * OUT_C + c) = v;
}

extern "C" void kernel_launch(void* const* d_in, const int* in_sizes, int n_in,
                              void* d_out, int out_size, void* d_ws, size_t ws_size,
                              hipStream_t stream) {
  const float* x = (const float*)d_in[0];   // [1024][1024]
  const float* T = (const float*)d_in[1];   // [1024][256]
  float* out = (float*)d_out;               // [1024][1056]

  const size_t mElems = (size_t)N_ROWS * OK;           // 262144
  const size_t needed = KS * mElems * 4                // part  8 MB
                      + mElems * 2                     // Mt  0.5 MB
                      + (size_t)N_ROWS * IN_F * 2      // xb    2 MB
                      + (size_t)OK * IN_F * 2;         // Tt  0.5 MB

  if (ws_size >= needed) {
    float* part = (float*)d_ws;
    __half* Mt  = (__half*)(part + KS * mElems);
    unsigned short* xb = (unsigned short*)(Mt + mElems);
    unsigned short* Tt = xb + (size_t)N_ROWS * IN_F;

    prep_kernel<<<dim3(576), dim3(256), 0, stream>>>(x, T, out, xb, Tt);
    gemm_mfma_kernel<<<dim3(16, 4, KS), dim3(256), 0, stream>>>(xb, Tt, part);
    reduce_kernel<<<dim3(256), dim3(256), 0, stream>>>(part, Mt);
    pairwise13_kernel<<<dim3(32, 16), dim3(256), 0, stream>>>(Mt, out);
  } else {
    float* M = (float*)d_ws;
    copy_x_kernel<<<dim3(N_ROWS), dim3(256), 0, stream>>>(x, out);
    gemm32_kernel<<<dim3(32, 8), dim3(256), 0, stream>>>(x, T, M);
    pairwise_kernel<<<dim3(32, 16), dim3(256), 0, stream>>>(M, out);
  }
}

// Round 17
// 33.809 us; speedup vs baseline: 5.1211x; 1.1357x over previous
//
#include <hip/hip_runtime.h>
#include <hip/hip_bf16.h>
#include <hip/hip_fp16.h>

// Problem: B=N=1024, in_f=1024, OUT_F=32, KD=8
// out[n][0:1024]   = x[n][:]
// M[n][o*8+k]      = sum_f x[n][f] * T[f][o*8+k]        (T flat [1024][256])
// out[n][1024+o]   = sum_{i != n} exp(-sum_k |M[i][o*8+k] - M[n][o*8+k]|)
//
// R16: 3 nodes. prep deleted: gemm stages straight from f32 x/T with
// in-register v_cvt_pk_bf16_f32 (same LDS layout/frags as R15); x->out copy
// fused into reduce_copy. pairwise13 (R15) verbatim.

#define N_ROWS 1024
#define IN_F   1024
#define OUT_C  1056
#define OK     256   // OUT_F*KD
#define KS     8     // K-split factor
#define KC     128   // K-chunk = IN_F/KS
#define LOG2E  1.44269504f

typedef __attribute__((ext_vector_type(8))) short bf16x8;
typedef __attribute__((ext_vector_type(4))) float f32x4;
typedef _Float16 hv2 __attribute__((ext_vector_type(2)));

__device__ __forceinline__ float fast_exp2(float x) {
#if __has_builtin(__builtin_amdgcn_exp2f)
  return __builtin_amdgcn_exp2f(x);   // v_exp_f32 = 2^x
#else
  return __expf(x * 0.6931472f);
#endif
}

// packed |.| : single v_and_b32 on the f16 pair
__device__ __forceinline__ hv2 habs2v(hv2 v) {
  unsigned u = __builtin_bit_cast(unsigned, v) & 0x7fff7fffu;
  return __builtin_bit_cast(hv2, u);
}

// RNE pack of two f32 -> u32 of 2 bf16 (lo = a, hi = b). Guide T12 recipe.
__device__ __forceinline__ unsigned cvt_pk_bf16(float a, float b) {
  unsigned r;
  asm("v_cvt_pk_bf16_f32 %0, %1, %2" : "=v"(r) : "v"(a), "v"(b));
  return r;
}

union HQ { uint4 q; hv2 h[4]; };

// ---------------- kernel 1: bf16 MFMA GEMM from raw f32 x/T ------------------
// grid (16,4,8) x 256. Same LDS layout + frag reads + MFMA + epilogue as R15;
// staging now reads f32 and converts in-register (xb/Tt buffers eliminated).
__global__ __launch_bounds__(256) void gemm_mfma2_kernel(
    const float* __restrict__ x,   // [1024][1024] f32
    const float* __restrict__ T,   // [1024][256] f32
    float* __restrict__ part) {    // [KS][1024][256]
  __shared__ unsigned short asw[64 * 128];  // A: row-major k-slabs, XOR-swizzled
  __shared__ unsigned short bsw[64 * 128];  // B: col-major via in-stage transpose
  const int m0 = blockIdx.x * 64;
  const int n0 = blockIdx.y * 64;
  const int k0 = blockIdx.z * KC;
  const int t  = threadIdx.x;

  // stage A: 64 rows x 128 k f32 = 2048 float4; cvt -> b64 swizzled writes
#pragma unroll
  for (int u = 0; u < 8; ++u) {
    int idx = u * 256 + t;
    int row = idx >> 5, fk = idx & 31;        // 32 float4 per row
    float4 v = *reinterpret_cast<const float4*>(
        x + (size_t)(m0 + row) * IN_F + k0 + fk * 4);
    unsigned lo = cvt_pk_bf16(v.x, v.y);
    unsigned hi = cvt_pk_bf16(v.z, v.w);
    int slot = fk >> 1, half = fk & 1;        // 16B slot + 8B half
    unsigned short* dst = asw + row * 128 + ((slot ^ (row & 15)) * 8) + half * 4;
    *reinterpret_cast<uint2*>(dst) = make_uint2(lo, hi);
  }
  // stage B (transpose in-stage): for col c, k-pair (kk,kk+1):
  // read T[kk][c],T[kk+1][c] (float2 along c, coalesced), pack along k, b32 write.
#pragma unroll
  for (int u = 0; u < 8; ++u) {
    int w2 = u * 256 + t;                     // 2048 units = 64 kk2 x 32 c2
    int c = (w2 & 31) * 2, kk = (w2 >> 5) * 2;
    const float* Tp = T + (size_t)(k0 + kk) * OK + n0 + c;
    float2 v0 = *reinterpret_cast<const float2*>(Tp);        // T[kk][c], T[kk][c+1]
    float2 v1 = *reinterpret_cast<const float2*>(Tp + OK);   // T[kk+1][c], [c+1]
    unsigned p0 = cvt_pk_bf16(v0.x, v1.x);    // col c:   (kk, kk+1)
    unsigned p1 = cvt_pk_bf16(v0.y, v1.y);    // col c+1: (kk, kk+1)
    int slot = kk >> 3, sub = kk & 7;
    *reinterpret_cast<unsigned*>(
        bsw + (c) * 128 + ((slot ^ (c & 15)) * 8) + sub) = p0;
    *reinterpret_cast<unsigned*>(
        bsw + (c + 1) * 128 + ((slot ^ ((c + 1) & 15)) * 8) + sub) = p1;
  }
  __syncthreads();

  const int l  = t & 63, w = t >> 6;
  const int lr = l & 15, lg = l >> 4;
  f32x4 acc0 = {0.f, 0.f, 0.f, 0.f};
  f32x4 acc1 = {0.f, 0.f, 0.f, 0.f};
  f32x4 acc2 = {0.f, 0.f, 0.f, 0.f};
  f32x4 acc3 = {0.f, 0.f, 0.f, 0.f};

  const int arow = w * 16 + lr;
  const int aswz = arow & 15;
#pragma unroll
  for (int kk = 0; kk < 4; ++kk) {
    int slotA = kk * 4 + lg;
    bf16x8 a = *reinterpret_cast<const bf16x8*>(
        asw + arow * 128 + ((slotA ^ aswz) * 8));
    int sb = (slotA ^ lr) * 8;
    bf16x8 b0 = *reinterpret_cast<const bf16x8*>(bsw + (lr)      * 128 + sb);
    bf16x8 b1 = *reinterpret_cast<const bf16x8*>(bsw + (16 + lr) * 128 + sb);
    bf16x8 b2 = *reinterpret_cast<const bf16x8*>(bsw + (32 + lr) * 128 + sb);
    bf16x8 b3 = *reinterpret_cast<const bf16x8*>(bsw + (48 + lr) * 128 + sb);
    acc0 = __builtin_amdgcn_mfma_f32_16x16x32_bf16(a, b0, acc0, 0, 0, 0);
    acc1 = __builtin_amdgcn_mfma_f32_16x16x32_bf16(a, b1, acc1, 0, 0, 0);
    acc2 = __builtin_amdgcn_mfma_f32_16x16x32_bf16(a, b2, acc2, 0, 0, 0);
    acc3 = __builtin_amdgcn_mfma_f32_16x16x32_bf16(a, b3, acc3, 0, 0, 0);
  }

  // C/D layout: col = lane&15, row = (lane>>4)*4 + reg
  float* dst = part + (size_t)blockIdx.z * (N_ROWS * OK)
             + (size_t)(m0 + w * 16 + lg * 4) * OK + n0 + lr;
#pragma unroll
  for (int r = 0; r < 4; ++r) {
    dst[(size_t)r * OK]      = acc0[r];
    dst[(size_t)r * OK + 16] = acc1[r];
    dst[(size_t)r * OK + 32] = acc2[r];
    dst[(size_t)r * OK + 48] = acc3[r];
  }
}

// ---------------- kernel 2: reduce part -> f16 Mt (transposed) + copy x ------
// grid 512 x 256. t<128: reduce 128 float4 groups -> Mt[o][n][k] * log2e.
// All threads: copy 512 float4 of x -> out[:,0:1024].
__global__ __launch_bounds__(256) void reduce_copy_kernel(
    const float* __restrict__ part, __half* __restrict__ Mt,
    const float* __restrict__ x, float* __restrict__ out) {
  const int b = blockIdx.x, t = threadIdx.x;

  if (t < 128) {
    int g = b * 128 + t;                      // 65536 float4 groups
    const float4* p = reinterpret_cast<const float4*>(part);
    float4 s = p[g];
#pragma unroll
    for (int sl = 1; sl < KS; ++sl) {
      float4 v = p[g + (size_t)sl * (N_ROWS * OK / 4)];
      s.x += v.x; s.y += v.y; s.z += v.z; s.w += v.w;
    }
    int n = g >> 6, c = (g & 63) * 4;
    int o = c >> 3, k = c & 7;
    __half2 h01 = __floats2half2_rn(s.x * LOG2E, s.y * LOG2E);
    __half2 h23 = __floats2half2_rn(s.z * LOG2E, s.w * LOG2E);
    uint2 wv = make_uint2(*reinterpret_cast<unsigned*>(&h01),
                          *reinterpret_cast<unsigned*>(&h23));
    *reinterpret_cast<uint2*>(Mt + (size_t)o * (N_ROWS * 8) + n * 8 + k) = wv;
  }

#pragma unroll
  for (int u = 0; u < 2; ++u) {
    int idx = b * 512 + u * 256 + t;          // 262144 float4 groups
    int row = idx >> 8, col4 = idx & 255;
    float4 v = *reinterpret_cast<const float4*>(x + (size_t)row * IN_F + col4 * 4);
    *reinterpret_cast<float4*>(out + (size_t)row * OUT_C + col4 * 4) = v;
  }
}

// ---------------- kernel 3: pairwise exp2(-L1) v13 (R15 verbatim) ------------
__global__ __launch_bounds__(256) void pairwise13_kernel(
    const __half* __restrict__ Mt, float* __restrict__ out) {
  __shared__ uint4 sm[N_ROWS];      // 16 KB: row n = 8 halves of Mt[o][n][:]
  __shared__ float red[4][64];

  int o  = blockIdx.x;
  int jt = blockIdx.y;
  int t  = threadIdx.x;

  const uint4* src = reinterpret_cast<const uint4*>(Mt + (size_t)o * (N_ROWS * 8));
#pragma unroll
  for (int u = 0; u < 4; ++u)
    sm[t + 256 * u] = src[t + 256 * u];   // fully coalesced, b128 both sides
  __syncthreads();

  int jl = t & 63, s = t >> 6;
  int j  = jt * 64 + jl;

  HQ ju; ju.q = sm[j];
  hv2 r0 = ju.h[0], r1 = ju.h[1], r2 = ju.h[2], r3 = ju.h[3];

  float acc = 0.f;
  const uint4* base = &sm[s * 256];
#pragma unroll 8
  for (int i = 0; i < 256; ++i) {
    HQ u_; u_.q = base[i];              // one ds_read_b128
    hv2 d2 = (habs2v(u_.h[0] - r0) + habs2v(u_.h[1] - r1)) +
             (habs2v(u_.h[2] - r2) + habs2v(u_.h[3] - r3));
    float d = (float)(d2.x + d2.y);     // 1 f16 add + 1 cvt
    acc += fast_exp2(-d);               // large d underflows to 0
  }
  if ((j >> 8) == s) acc -= 1.0f;       // exact self term exp2(0)=1

  red[s][jl] = acc;
  __syncthreads();

  if (t < 64) {
    float v = red[0][t] + red[1][t] + red[2][t] + red[3][t];
    int jj = jt * 64 + t;
    out[(size_t)jj * OUT_C + 1024 + o] = v;
  }
}

// ---------------- fallback path (small ws): f32 single-pass ------------------
#define BK 16
__global__ __launch_bounds__(256) void gemm32_kernel(
    const float* __restrict__ A, const float* __restrict__ Bm, float* __restrict__ M) {
  __shared__ float as2[BK][32];
  __shared__ float bs2[BK][32];
  int m0 = blockIdx.x * 32;
  int n0 = blockIdx.y * 32;
  int t  = threadIdx.x;
  int ty = t >> 4, tx = t & 15;
  float c00 = 0.f, c01 = 0.f, c10 = 0.f, c11 = 0.f;
  for (int k0 = 0; k0 < IN_F; k0 += BK) {
    if (t < 128) {
      int row = t >> 2, q = t & 3;
      float4 v = *reinterpret_cast<const float4*>(A + (size_t)(m0 + row) * IN_F + k0 + q * 4);
      as2[q * 4 + 0][row] = v.x; as2[q * 4 + 1][row] = v.y;
      as2[q * 4 + 2][row] = v.z; as2[q * 4 + 3][row] = v.w;
    } else {
      int tt = t - 128;
      int row = tt >> 3, q = tt & 7;
      float4 v = *reinterpret_cast<const float4*>(Bm + (size_t)(k0 + row) * OK + n0 + q * 4);
      *reinterpret_cast<float4*>(&bs2[row][q * 4]) = v;
    }
    __syncthreads();
#pragma unroll
    for (int kk = 0; kk < BK; ++kk) {
      float2 a = *reinterpret_cast<const float2*>(&as2[kk][ty * 2]);
      float2 b = *reinterpret_cast<const float2*>(&bs2[kk][tx * 2]);
      c00 += a.x * b.x; c01 += a.x * b.y;
      c10 += a.y * b.x; c11 += a.y * b.y;
    }
    __syncthreads();
  }
  int r = m0 + ty * 2, c = n0 + tx * 2;
  M[(size_t)r * OK + c]           = c00 * LOG2E;
  M[(size_t)r * OK + c + 1]       = c01 * LOG2E;
  M[(size_t)(r + 1) * OK + c]     = c10 * LOG2E;
  M[(size_t)(r + 1) * OK + c + 1] = c11 * LOG2E;
}

__global__ __launch_bounds__(256) void pairwise_kernel(
    const float* __restrict__ M, float* __restrict__ out) {
  __shared__ float sm[N_ROWS][8];
  __shared__ float red[4][64];
  int o  = blockIdx.x;
  int jt = blockIdx.y;
  int t  = threadIdx.x;
#pragma unroll
  for (int idx = t; idx < 2048; idx += 256) {
    int row = idx >> 1, half = idx & 1;
    *reinterpret_cast<float4*>(&sm[row][half * 4]) =
        *reinterpret_cast<const float4*>(M + (size_t)row * OK + o * 8 + half * 4);
  }
  __syncthreads();
  int jl = t & 63, s = t >> 6;
  int j  = jt * 64 + jl;
  float4 ra = *reinterpret_cast<const float4*>(&sm[j][0]);
  float4 rb = *reinterpret_cast<const float4*>(&sm[j][4]);
  float acc = 0.f;
  const float* base = &sm[s * 256][0];
#pragma unroll 4
  for (int i = 0; i < 256; ++i) {
    float4 va = *reinterpret_cast<const float4*>(base + i * 8);
    float4 vb = *reinterpret_cast<const float4*>(base + i * 8 + 4);
    float d = fabsf(va.x - ra.x) + fabsf(va.y - ra.y) +
              fabsf(va.z - ra.z) + fabsf(va.w - ra.w) +
              fabsf(vb.x - rb.x) + fabsf(vb.y - rb.y) +
              fabsf(vb.z - rb.z) + fabsf(vb.w - rb.w);
    acc += fast_exp2(-d);
  }
  if ((j >> 8) == s) acc -= 1.0f;
  red[s][jl] = acc;
  __syncthreads();
  if (t < 64) {
    float v = red[0][t] + red[1][t] + red[2][t] + red[3][t];
    int jj = jt * 64 + t;
    out[(size_t)jj * OUT_C + 1024 + o] = v;
  }
}

__global__ __launch_bounds__(256) void copy_x_kernel(
    const float* __restrict__ x, float* __restrict__ out) {
  int n = blockIdx.x;
  int c = threadIdx.x * 4;
  float4 v = *reinterpret_cast<const float4*>(x + (size_t)n * IN_F + c);
  *reinterpret_cast<float4*>(out + (size_t)n * OUT_C + c) = v;
}

extern "C" void kernel_launch(void* const* d_in, const int* in_sizes, int n_in,
                              void* d_out, int out_size, void* d_ws, size_t ws_size,
                              hipStream_t stream) {
  const float* x = (const float*)d_in[0];   // [1024][1024]
  const float* T = (const float*)d_in[1];   // [1024][256]
  float* out = (float*)d_out;               // [1024][1056]

  const size_t mElems = (size_t)N_ROWS * OK;           // 262144
  const size_t needed = KS * mElems * 4                // part  8 MB
                      + mElems * 2;                    // Mt  0.5 MB

  if (ws_size >= needed) {
    float* part = (float*)d_ws;
    __half* Mt  = (__half*)(part + KS * mElems);

    gemm_mfma2_kernel<<<dim3(16, 4, KS), dim3(256), 0, stream>>>(x, T, part);
    reduce_copy_kernel<<<dim3(512), dim3(256), 0, stream>>>(part, Mt, x, out);
    pairwise13_kernel<<<dim3(32, 16), dim3(256), 0, stream>>>(Mt, out);
  } else {
    float* M = (float*)d_ws;
    copy_x_kernel<<<dim3(N_ROWS), dim3(256), 0, stream>>>(x, out);
    gemm32_kernel<<<dim3(32, 8), dim3(256), 0, stream>>>(x, T, M);
    pairwise_kernel<<<dim3(32, 16), dim3(256), 0, stream>>>(M, out);
  }
}